// Round 9
// baseline (3055.802 us; speedup 1.0000x reference)
//
#include <hip/hip_runtime.h>

#define BB 64
#define TT 1000
#define II 16
#define HH 512
#define OO 8
#define NOISE_STD 0.05f
#define ALPHA 0.2f

#define NGROUPS 16   // batch groups; each owns BPG=4 batches, staggered one per phase
#define BPG 4
#define NSLABS 8     // row slabs (WGs) per group, 64 rows each
#define JS 64
#define NTHREADS 512 // waves 0-3: compute (k-slice 128 each); waves 4-7: service (batch wid-4)
#define NBLOCKS (NGROUPS * NSLABS)   // 128

// d_ws: rtag[2][BB][HH] u64 = (tag<<32 | r_bits), parity-double-buffered.
// Equality-tag protocol (0xAA poison / stale never falsely matches a fresh await;
// cross-call stale tag==t match delivers bit-identical deterministic data -> benign).
// Stagger gives each publish ~3 phases (>= MALL RT) before its consumer reads it.

#define AGENT_LD(P)   __hip_atomic_load((P), __ATOMIC_RELAXED, __HIP_MEMORY_SCOPE_AGENT)
#define AGENT_ST(P,V) __hip_atomic_store((P), (V), __ATOMIC_RELAXED, __HIP_MEMORY_SCOPE_AGENT)

// raw barrier: drains LDS (lgkmcnt) ONLY. Pre-issued global polls stay in flight
// across it (a plain __syncthreads would emit s_waitcnt vmcnt(0) and expose the RT).
#define BAR() do { \
    asm volatile("s_waitcnt lgkmcnt(0)" ::: "memory"); \
    __builtin_amdgcn_sched_barrier(0); \
    __builtin_amdgcn_s_barrier(); \
    __builtin_amdgcn_sched_barrier(0); \
} while (0)

__global__ void __launch_bounds__(NTHREADS, 1) rnn_kernel(
    const float* __restrict__ x, const float* __restrict__ noise,
    const float* __restrict__ wi, const float* __restrict__ si,
    const float* __restrict__ wrec, const float* __restrict__ wo,
    const float* __restrict__ so, const float* __restrict__ h0,
    float* __restrict__ out, unsigned long long* rtag)
{
    __shared__ __align__(16) float zpart[4][4][JS];  // [phase][kchunk][row]  4 KB
    __shared__ __align__(16) float rlds[4][HH];      // [phase][k] staged r   8 KB

    const int tid  = threadIdx.x;
    const int lane = tid & 63;
    const int wid  = tid >> 6;

    const int xcd  = blockIdx.x & 7;          // XCD-packing heuristic only
    const int idx  = blockIdx.x >> 3;         // 0..15
    const int grp  = xcd * 2 + (idx >> 3);    // 0..15
    const int slab = idx & 7;                 // 0..7
    const int gb   = grp * BPG;
    const int j0   = slab * JS;

    if (wid < 4) {
        // ========== compute wave: rows j0+lane, k-slice [wid*128, +128) ==========
        float w_reg[128];
        {
            const float4* wrow = (const float4*)(wrec + (size_t)(j0 + lane) * HH + (wid << 7));
            #pragma unroll
            for (int c4 = 0; c4 < 32; ++c4) {
                float4 v = wrow[c4];
                w_reg[4*c4+0] = v.x; w_reg[4*c4+1] = v.y;
                w_reg[4*c4+2] = v.z; w_reg[4*c4+3] = v.w;
            }
        }
        const float r0lo = tanhf(h0[(wid << 7) + lane]);
        const float r0hi = tanhf(h0[(wid << 7) + 64 + lane]);
        unsigned long long pre0 = 0, pre1 = 0;   // pre-issued poll values

        for (int s = 0; s < 4 * TT; ++s) {
            const int q = s & 3;       // phase == batch index within group
            const int t = s >> 2;
            float rb0v, rb1v;          // r[wid*128 + lane], r[wid*128 + 64 + lane]
            if (t == 0) { rb0v = r0lo; rb1v = r0hi; }
            else {
                const unsigned int tg = (unsigned int)t;
                unsigned long long v0 = pre0, v1 = pre1;   // issued last phase
                if (((unsigned int)(v0 >> 32) != tg) || ((unsigned int)(v1 >> 32) != tg)) {
                    // rare fallback: fresh agent polls (guaranteed liveness)
                    const unsigned long long* sp = rtag + (size_t)(t & 1) * (BB * HH)
                                                  + (size_t)(gb + q) * HH + (wid << 7) + lane;
                    do { v0 = AGENT_LD(sp); v1 = AGENT_LD(sp + 64); }
                    while (((unsigned int)(v0 >> 32) != tg) ||
                           ((unsigned int)(v1 >> 32) != tg));
                }
                rb0v = __uint_as_float((unsigned int)v0);
                rb1v = __uint_as_float((unsigned int)v1);
            }
            {   // pre-issue next phase's poll; returns while we matvec + cross BAR
                const int pn = (q + 1) & 3;
                const int tn = t + (pn == 0 ? 1 : 0);
                if (tn >= 1 && tn < TT) {
                    const unsigned long long* sp = rtag + (size_t)(tn & 1) * (BB * HH)
                                                  + (size_t)(gb + pn) * HH + (wid << 7) + lane;
                    pre0 = AGENT_LD(sp);
                    pre1 = AGENT_LD(sp + 64);
                }
            }
            // stage r for the out duty + matvec via readlane broadcast (no LDS reads)
            rlds[q][(wid << 7) + lane]      = rb0v;
            rlds[q][(wid << 7) + 64 + lane] = rb1v;
            const unsigned int rbits0 = __float_as_uint(rb0v);
            const unsigned int rbits1 = __float_as_uint(rb1v);
            float acc0 = 0.f, acc1 = 0.f;
            #pragma unroll
            for (int c = 0; c < 64; ++c) {
                acc0 += w_reg[c]      * __uint_as_float(__builtin_amdgcn_readlane(rbits0, c));
                acc1 += w_reg[64 + c] * __uint_as_float(__builtin_amdgcn_readlane(rbits1, c));
            }
            zpart[q][wid][lane] = acc0 + acc1;
            BAR();
        }
        // compute waves exit
    } else {
        // ========== service wave: owns batch b = gb + (wid-4) for this slab ==========
        const int p = wid - 4;
        const int b = gb + p;
        float hreg = h0[j0 + lane];            // h(b, row j0+lane)
        float wiF[16];
        #pragma unroll
        for (int i = 0; i < II; ++i) wiF[i] = si[i] * wi[i * HH + j0 + lane];
        float wo_r[8][8];
        if (slab == p) {                        // out duty lives on slab p only
            float so_[8];
            #pragma unroll
            for (int o = 0; o < 8; ++o) so_[o] = so[o];
            #pragma unroll
            for (int m = 0; m < 8; ++m) {
                const float4* wrow = (const float4*)(wo + (size_t)(lane + (m << 6)) * OO);
                float4 wa = wrow[0], wb2 = wrow[1];
                wo_r[m][0] = wa.x * so_[0];  wo_r[m][1] = wa.y * so_[1];
                wo_r[m][2] = wa.z * so_[2];  wo_r[m][3] = wa.w * so_[3];
                wo_r[m][4] = wb2.x * so_[4]; wo_r[m][5] = wb2.y * so_[5];
                wo_r[m][6] = wb2.z * so_[6]; wo_r[m][7] = wb2.w * so_[7];
            }
        }
        float nz_cur = noise[((size_t)b * TT + 0) * HH + j0 + lane];
        float nz_pend = 0.f;
        float4 xf0, xf1, xf2, xf3;
        float xp_cur;
        {
            const float4* xb = (const float4*)(x + ((size_t)b * TT + 0) * II);
            float4 a = xb[0], c = xb[1], d = xb[2], e = xb[3];
            xp_cur = a.x*wiF[0] +a.y*wiF[1] +a.z*wiF[2] +a.w*wiF[3]
                   + c.x*wiF[4] +c.y*wiF[5] +c.z*wiF[6] +c.w*wiF[7]
                   + d.x*wiF[8] +d.y*wiF[9] +d.z*wiF[10]+d.w*wiF[11]
                   + e.x*wiF[12]+e.y*wiF[13]+e.z*wiF[14]+e.w*wiF[15];
        }

        #define RED_(A, O) { float v_ = (A); \
            v_ += __shfl_xor(v_, 1);  v_ += __shfl_xor(v_, 2); \
            v_ += __shfl_xor(v_, 4);  v_ += __shfl_xor(v_, 8); \
            v_ += __shfl_xor(v_, 16); v_ += __shfl_xor(v_, 32); \
            if (lane == (O)) res = v_; }

        auto do_out = [&](int tau, int slot) {   // out[b][tau][:] = r(b,tau+1) @ wo_full
            float a0=0,a1=0,a2=0,a3=0,a4=0,a5=0,a6=0,a7=0;
            #pragma unroll
            for (int m = 0; m < 8; ++m) {
                float rv = rlds[slot][lane + (m << 6)];
                a0 += rv*wo_r[m][0]; a1 += rv*wo_r[m][1]; a2 += rv*wo_r[m][2]; a3 += rv*wo_r[m][3];
                a4 += rv*wo_r[m][4]; a5 += rv*wo_r[m][5]; a6 += rv*wo_r[m][6]; a7 += rv*wo_r[m][7];
            }
            float res = 0.f;
            RED_(a0,0) RED_(a1,1) RED_(a2,2) RED_(a3,3)
            RED_(a4,4) RED_(a5,5) RED_(a6,6) RED_(a7,7)
            if (lane < 8) out[((size_t)b * TT + tau) * OO + lane] = res;
        };

        for (int s = 0; s < 4 * TT; ++s) {
            // duty A (at s = 4t+p+1): reduce + h-update + publish r(t+1); issue t+1 prefetches
            if (s >= 1 && ((s - 1) & 3) == p) {
                const int td = (s - 1) >> 2;
                float z = zpart[p][0][lane] + zpart[p][1][lane]
                        + zpart[p][2][lane] + zpart[p][3][lane];
                float hn = hreg + NOISE_STD * nz_cur + ALPHA * (z + xp_cur - hreg);
                hreg = hn;
                float rnew = tanhf(hn);
                unsigned long long pv = ((unsigned long long)(unsigned int)(td + 1) << 32)
                                      | (unsigned long long)__float_as_uint(rnew);
                AGENT_ST(rtag + (size_t)((td + 1) & 1) * (BB * HH)
                              + (size_t)b * HH + j0 + lane, pv);
                if (td + 1 < TT) {
                    nz_pend = noise[((size_t)b * TT + (td + 1)) * HH + j0 + lane];
                    const float4* xb = (const float4*)(x + ((size_t)b * TT + (td + 1)) * II);
                    xf0 = xb[0]; xf1 = xb[1]; xf2 = xb[2]; xf3 = xb[3];
                }
            }
            // duty B (at s = 4(tau+1)+p+2): out[b][tau] from staged r(b,tau+1)
            if (s >= 2 && ((s - 2) & 3) == p) {
                const int tau = ((s - 2) >> 2) - 1;
                if (tau >= 0 && slab == p) do_out(tau, p);
            }
            // duty C (at s = 4t+p+3): fold prefetches for t+1
            if (s >= 3 && ((s - 3) & 3) == p) {
                const int tnx = ((s - 3) >> 2) + 1;
                if (tnx < TT) {
                    xp_cur = xf0.x*wiF[0] +xf0.y*wiF[1] +xf0.z*wiF[2] +xf0.w*wiF[3]
                           + xf1.x*wiF[4] +xf1.y*wiF[5] +xf1.z*wiF[6] +xf1.w*wiF[7]
                           + xf2.x*wiF[8] +xf2.y*wiF[9] +xf2.z*wiF[10]+xf2.w*wiF[11]
                           + xf3.x*wiF[12]+xf3.y*wiF[13]+xf3.z*wiF[14]+xf3.w*wiF[15];
                    nz_cur = nz_pend;
                }
            }
            BAR();
        }
        // ---- epilogue ----
        if (p == 3) {   // final reduce(3, TT-1) lands past the loop; publish tag TT
            float z = zpart[3][0][lane] + zpart[3][1][lane]
                    + zpart[3][2][lane] + zpart[3][3][lane];
            float hn = hreg + NOISE_STD * nz_cur + ALPHA * (z + xp_cur - hreg);
            float rnew = tanhf(hn);
            unsigned long long pv = ((unsigned long long)(unsigned int)TT << 32)
                                  | (unsigned long long)__float_as_uint(rnew);
            AGENT_ST(rtag + (size_t)(TT & 1) * (BB * HH) + (size_t)b * HH + j0 + lane, pv);
        }
        if (slab == p) {
            if (p >= 2) do_out(TT - 2, p);   // out duties scheduled past loop end
            // final out[b][TT-1] from r(b,TT): poll 8 slots/lane into registers
            float rv[8];
            const unsigned long long* sp =
                rtag + (size_t)(TT & 1) * (BB * HH) + (size_t)b * HH + lane;
            #pragma unroll
            for (int m = 0; m < 8; ++m) {
                unsigned long long v;
                do { v = AGENT_LD(sp + (m << 6)); }
                while ((unsigned int)(v >> 32) != (unsigned int)TT);
                rv[m] = __uint_as_float((unsigned int)v);
            }
            float a0=0,a1=0,a2=0,a3=0,a4=0,a5=0,a6=0,a7=0;
            #pragma unroll
            for (int m = 0; m < 8; ++m) {
                float rvm = rv[m];
                a0 += rvm*wo_r[m][0]; a1 += rvm*wo_r[m][1]; a2 += rvm*wo_r[m][2]; a3 += rvm*wo_r[m][3];
                a4 += rvm*wo_r[m][4]; a5 += rvm*wo_r[m][5]; a6 += rvm*wo_r[m][6]; a7 += rvm*wo_r[m][7];
            }
            float res = 0.f;
            RED_(a0,0) RED_(a1,1) RED_(a2,2) RED_(a3,3)
            RED_(a4,4) RED_(a5,5) RED_(a6,6) RED_(a7,7)
            if (lane < 8) out[((size_t)b * TT + (TT - 1)) * OO + lane] = res;
        }
        #undef RED_
    }
}

extern "C" void kernel_launch(void* const* d_in, const int* in_sizes, int n_in,
                              void* d_out, int out_size, void* d_ws, size_t ws_size,
                              hipStream_t stream) {
    const float* x     = (const float*)d_in[0];
    const float* noise = (const float*)d_in[1];
    const float* wi    = (const float*)d_in[2];
    const float* si    = (const float*)d_in[3];
    const float* wrec  = (const float*)d_in[4];
    const float* wo    = (const float*)d_in[5];
    const float* so    = (const float*)d_in[6];
    const float* h0    = (const float*)d_in[7];
    float* out = (float*)d_out;
    unsigned long long* rtag = (unsigned long long*)d_ws;   // 512 KB

    (void)in_sizes; (void)n_in; (void)out_size; (void)ws_size;

    void* args[] = {(void*)&x, (void*)&noise, (void*)&wi, (void*)&si,
                    (void*)&wrec, (void*)&wo, (void*)&so, (void*)&h0,
                    (void*)&out, (void*)&rtag};
    hipLaunchCooperativeKernel((void*)rnn_kernel, dim3(NBLOCKS), dim3(NTHREADS),
                               args, 0, stream);
}

// Round 10
// 2354.914 us; speedup vs baseline: 1.2976x; 1.2976x over previous
//
#include <hip/hip_runtime.h>

#define BB 64
#define TT 1000
#define II 16
#define HH 512
#define OO 8
#define NOISE_STD 0.05f
#define ALPHA 0.2f

#define NGROUPS 32   // batch groups (independent sync domains)
#define BPG 2        // batches per group
#define NSLABS 8     // row slabs (WGs) per group
#define JS 64        // rows per slab
#define NTHREADS 512 // 8 waves; wave w owns k-slice [w*64, w*64+64)
#define NBLOCKS (NGROUPS * NSLABS)   // 256 = one WG per CU

// d_ws: rtag[2][BB][HH] u64 = (tag<<32 | r_bits), parity-double-buffered.
// Equality-tag protocol: a slot awaiting tag t holds only {stale != t, t};
// 0xAA poison never matches. All polls are agent-scope atomic loads
// (proven-visible path) — pipelined 3-deep to cut detection granularity
// from ~RT to ~RT/3. Tags are monotonic per slot, so any slot that passes
// the check holds the correct value.

#define AGENT_ST(P,V) __hip_atomic_store((P), (V), __ATOMIC_RELAXED, __HIP_MEMORY_SCOPE_AGENT)

__global__ void __launch_bounds__(NTHREADS, 1) rnn_kernel(
    const float* __restrict__ x, const float* __restrict__ noise,
    const float* __restrict__ wi, const float* __restrict__ si,
    const float* __restrict__ wrec, const float* __restrict__ wo,
    const float* __restrict__ so, const float* __restrict__ h0,
    float* __restrict__ out, unsigned long long* rtag)
{
    __shared__ __align__(16) float rlds[2][BPG][HH];          // staged r       8 KB
    __shared__ __align__(16) float zpart[2][NSLABS][BPG][JS]; // parity-dbuf    8 KB
    __shared__ __align__(16) float xpbuf[2][BPG][JS];         //                1 KB
    __shared__ __align__(16) float nzbuf[2][BPG][JS];         //                1 KB

    const int tid  = threadIdx.x;
    const int lane = tid & 63;
    const int wid  = tid >> 6;

    const int xcd  = blockIdx.x & 7;          // XCD-packing heuristic only
    const int bidx = blockIdx.x >> 3;         // 0..31
    const int grp  = xcd * 4 + (bidx >> 3);   // 0..31
    const int slab = bidx & 7;                // 0..7
    const int gb   = grp * BPG;
    const int j0   = slab * JS;

    // ---- one-time staging ----
    float w_reg[64];   // wrec row (j0+lane), k-slice [wid*64, +64)
    {
        const float4* wrow = (const float4*)(wrec + (size_t)(j0 + lane) * HH + wid * 64);
        #pragma unroll
        for (int c = 0; c < 16; ++c) {
            float4 v = wrow[c];
            w_reg[4*c+0] = v.x; w_reg[4*c+1] = v.y;
            w_reg[4*c+2] = v.z; w_reg[4*c+3] = v.w;
        }
    }

    float hreg = 0.f;
    if (wid < BPG) hreg = h0[j0 + lane];      // h for (batch gb+wid, row j0+lane)

    float wiF_r[16];                           // waves 2,3: x-projection weights
    if (wid == 2 || wid == 3) {
        #pragma unroll
        for (int i = 0; i < 16; ++i) wiF_r[i] = si[i] * wi[i * HH + j0 + lane];
    }
    float wo_r[8][8];                          // waves 4,5: output weights
    if (wid == 4 || wid == 5) {
        float so_[8];
        #pragma unroll
        for (int o = 0; o < 8; ++o) so_[o] = so[o];
        #pragma unroll
        for (int m = 0; m < 8; ++m) {
            const float4* wrow = (const float4*)(wo + (size_t)(lane + 64 * m) * OO);
            float4 wa = wrow[0], wb2 = wrow[1];
            wo_r[m][0] = wa.x  * so_[0]; wo_r[m][1] = wa.y  * so_[1];
            wo_r[m][2] = wa.z  * so_[2]; wo_r[m][3] = wa.w  * so_[3];
            wo_r[m][4] = wb2.x * so_[4]; wo_r[m][5] = wb2.y * so_[5];
            wo_r[m][6] = wb2.z * so_[6]; wo_r[m][7] = wb2.w * so_[7];
        }
    }

    // r_0 = tanh(h0): own slice in regs + staged for out waves
    unsigned int rb0, rb1;
    {
        float rv = tanhf(h0[wid * 64 + lane]);
        rb0 = __float_as_uint(rv);
        rb1 = rb0;
        rlds[0][0][wid * 64 + lane] = rv;
        rlds[0][1][wid * 64 + lane] = rv;
    }
    if (wid == 2 || wid == 3) {   // xp_0
        const int b = wid - 2;
        const float4* xb = (const float4*)(x + ((size_t)(gb + b) * TT + 0) * II);
        float4 x0 = xb[0], x1 = xb[1], x2 = xb[2], x3 = xb[3];
        xpbuf[0][b][lane] =
              x0.x*wiF_r[0]  + x0.y*wiF_r[1]  + x0.z*wiF_r[2]  + x0.w*wiF_r[3]
            + x1.x*wiF_r[4]  + x1.y*wiF_r[5]  + x1.z*wiF_r[6]  + x1.w*wiF_r[7]
            + x2.x*wiF_r[8]  + x2.y*wiF_r[9]  + x2.z*wiF_r[10] + x2.w*wiF_r[11]
            + x3.x*wiF_r[12] + x3.y*wiF_r[13] + x3.z*wiF_r[14] + x3.w*wiF_r[15];
    }
    __syncthreads();

    for (int t = 0; t < TT; ++t) {
        const int par = t & 1;
        const int nxt = (t + 1) & 1;

        // waves 2,3: issue noise(t) + x(t+1) loads early (consumed pre-S1/post-S1)
        float nzld = 0.f;
        float4 xf0, xf1, xf2, xf3;
        if (wid == 2 || wid == 3) {
            const int b = wid - 2;
            nzld = noise[((size_t)(gb + b) * TT + t) * HH + j0 + lane];
            if (t + 1 < TT) {
                const float4* xb = (const float4*)(x + ((size_t)(gb + b) * TT + (t + 1)) * II);
                xf0 = xb[0]; xf1 = xb[1]; xf2 = xb[2]; xf3 = xb[3];
            }
        }

        // per-wave rendezvous: 3-deep pipelined agent-scope polls on OWN slice.
        // Check the oldest while two newer pairs are in flight -> detection
        // granularity ~RT/3 instead of ~RT. Wave-uniform exit via __all.
        if (t > 0) {
            const unsigned long long* s0 =
                rtag + (size_t)par * (BB * HH) + (size_t)gb * HH + wid * 64 + lane;
            const unsigned long long* s1 = s0 + HH;
            const unsigned int tg = (unsigned int)t;
            #define LD0_ __hip_atomic_load(s0, __ATOMIC_RELAXED, __HIP_MEMORY_SCOPE_AGENT)
            #define LD1_ __hip_atomic_load(s1, __ATOMIC_RELAXED, __HIP_MEMORY_SCOPE_AGENT)
            unsigned long long pa0 = LD0_, pa1 = LD1_;
            unsigned long long pb0 = LD0_, pb1 = LD1_;
            unsigned long long pc0 = LD0_, pc1 = LD1_;
            unsigned long long r0v, r1v;
            for (;;) {
                bool ok = ((unsigned int)(pa0 >> 32) == tg) &
                          ((unsigned int)(pa1 >> 32) == tg);
                if (__all(ok)) { r0v = pa0; r1v = pa1; break; }
                pa0 = LD0_; pa1 = LD1_;
                ok = ((unsigned int)(pb0 >> 32) == tg) &
                     ((unsigned int)(pb1 >> 32) == tg);
                if (__all(ok)) { r0v = pb0; r1v = pb1; break; }
                pb0 = LD0_; pb1 = LD1_;
                ok = ((unsigned int)(pc0 >> 32) == tg) &
                     ((unsigned int)(pc1 >> 32) == tg);
                if (__all(ok)) { r0v = pc0; r1v = pc1; break; }
                pc0 = LD0_; pc1 = LD1_;
            }
            #undef LD0_
            #undef LD1_
            rb0 = (unsigned int)r0v;
            rb1 = (unsigned int)r1v;
            rlds[par][0][wid * 64 + lane] = __uint_as_float(rb0);
            rlds[par][1][wid * 64 + lane] = __uint_as_float(rb1);
        }

        // matvec on own slice: w in regs, r broadcast via v_readlane
        float a0 = 0.f, a1 = 0.f;
        #pragma unroll
        for (int c = 0; c < 64; ++c) {
            float r0 = __uint_as_float(__builtin_amdgcn_readlane(rb0, c));
            float r1 = __uint_as_float(__builtin_amdgcn_readlane(rb1, c));
            a0 += w_reg[c] * r0;
            a1 += w_reg[c] * r1;
        }
        zpart[par][wid][0][lane] = a0;
        zpart[par][wid][1][lane] = a1;
        if (wid == 2 || wid == 3)               // hand noise(t) to the reducers
            nzbuf[par][wid - 2][lane] = nzld;
        __syncthreads();   // S1 (only barrier): zpart/rlds/nzbuf[par] ready

        if (wid < BPG) {
            // reduce 8 k-slices + h-update + tagged publish (b=wid, j=lane)
            // pure LDS+VALU path: no global loads before the publish store
            float z = 0.f;
            #pragma unroll
            for (int k8 = 0; k8 < 8; ++k8) z += zpart[par][k8][wid][lane];
            float xp = xpbuf[par][wid][lane];
            float nz = nzbuf[par][wid][lane];
            float hn = hreg + NOISE_STD * nz + ALPHA * (z + xp - hreg);
            hreg = hn;
            float rnew = tanhf(hn);
            unsigned long long pv =
                ((unsigned long long)(unsigned int)(t + 1) << 32)
              | (unsigned long long)__float_as_uint(rnew);
            AGENT_ST(rtag + (size_t)nxt * (BB * HH)
                          + (size_t)(gb + wid) * HH + j0 + lane, pv);
        } else if (wid == 2 || wid == 3) {
            // x-projection for step t+1 (off critical path)
            const int b = wid - 2;
            if (t + 1 < TT) {
                xpbuf[nxt][b][lane] =
                      xf0.x*wiF_r[0]  + xf0.y*wiF_r[1]  + xf0.z*wiF_r[2]  + xf0.w*wiF_r[3]
                    + xf1.x*wiF_r[4]  + xf1.y*wiF_r[5]  + xf1.z*wiF_r[6]  + xf1.w*wiF_r[7]
                    + xf2.x*wiF_r[8]  + xf2.y*wiF_r[9]  + xf2.z*wiF_r[10] + xf2.w*wiF_r[11]
                    + xf3.x*wiF_r[12] + xf3.y*wiF_r[13] + xf3.z*wiF_r[14] + xf3.w*wiF_r[15];
            }
        } else if (wid == 4 || wid == 5) {
            // out[t-1] = r_t @ wo_full — off the critical path
            const int b = wid - 4;
            if (t > 0) {
                float acc0=0.f,acc1=0.f,acc2=0.f,acc3=0.f,
                      acc4=0.f,acc5=0.f,acc6=0.f,acc7=0.f;
                #pragma unroll
                for (int m = 0; m < 8; ++m) {
                    float rv = rlds[par][b][lane + 64 * m];
                    acc0 += rv * wo_r[m][0]; acc1 += rv * wo_r[m][1];
                    acc2 += rv * wo_r[m][2]; acc3 += rv * wo_r[m][3];
                    acc4 += rv * wo_r[m][4]; acc5 += rv * wo_r[m][5];
                    acc6 += rv * wo_r[m][6]; acc7 += rv * wo_r[m][7];
                }
                float res = 0.f;
                #define RED_(A, O) { float v_ = A; \
                    v_ += __shfl_xor(v_, 1);  v_ += __shfl_xor(v_, 2); \
                    v_ += __shfl_xor(v_, 4);  v_ += __shfl_xor(v_, 8); \
                    v_ += __shfl_xor(v_, 16); v_ += __shfl_xor(v_, 32); \
                    if (lane == O) res = v_; }
                RED_(acc0, 0) RED_(acc1, 1) RED_(acc2, 2) RED_(acc3, 3)
                RED_(acc4, 4) RED_(acc5, 5) RED_(acc6, 6) RED_(acc7, 7)
                #undef RED_
                if (lane < 8)
                    out[((size_t)(gb + b) * TT + (t - 1)) * OO + lane] = res;
            }
        }
        // waves 6,7 have nothing post-S1 -> earliest pollers of t+1
    }

    // epilogue: poll r_TT (parity 0, tag TT), stage, emit out[TT-1]
    {
        const unsigned long long* s0 = rtag + (size_t)gb * HH + wid * 64 + lane;
        unsigned long long v0, v1;
        const unsigned int tg = (unsigned int)TT;
        do {
            v0 = __hip_atomic_load(s0,      __ATOMIC_RELAXED, __HIP_MEMORY_SCOPE_AGENT);
            v1 = __hip_atomic_load(s0 + HH, __ATOMIC_RELAXED, __HIP_MEMORY_SCOPE_AGENT);
        } while ((unsigned int)(v0 >> 32) != tg || (unsigned int)(v1 >> 32) != tg);
        rlds[0][0][wid * 64 + lane] = __uint_as_float((unsigned int)v0);
        rlds[0][1][wid * 64 + lane] = __uint_as_float((unsigned int)v1);
    }
    __syncthreads();
    if (wid == 4 || wid == 5) {
        const int b = wid - 4;
        float acc0=0.f,acc1=0.f,acc2=0.f,acc3=0.f,acc4=0.f,acc5=0.f,acc6=0.f,acc7=0.f;
        #pragma unroll
        for (int m = 0; m < 8; ++m) {
            float rv = rlds[0][b][lane + 64 * m];
            acc0 += rv * wo_r[m][0]; acc1 += rv * wo_r[m][1];
            acc2 += rv * wo_r[m][2]; acc3 += rv * wo_r[m][3];
            acc4 += rv * wo_r[m][4]; acc5 += rv * wo_r[m][5];
            acc6 += rv * wo_r[m][6]; acc7 += rv * wo_r[m][7];
        }
        float res = 0.f;
        #define RED_(A, O) { float v_ = A; \
            v_ += __shfl_xor(v_, 1);  v_ += __shfl_xor(v_, 2); \
            v_ += __shfl_xor(v_, 4);  v_ += __shfl_xor(v_, 8); \
            v_ += __shfl_xor(v_, 16); v_ += __shfl_xor(v_, 32); \
            if (lane == O) res = v_; }
        RED_(acc0, 0) RED_(acc1, 1) RED_(acc2, 2) RED_(acc3, 3)
        RED_(acc4, 4) RED_(acc5, 5) RED_(acc6, 6) RED_(acc7, 7)
        #undef RED_
        if (lane < 8)
            out[((size_t)(gb + b) * TT + (TT - 1)) * OO + lane] = res;
    }
}

extern "C" void kernel_launch(void* const* d_in, const int* in_sizes, int n_in,
                              void* d_out, int out_size, void* d_ws, size_t ws_size,
                              hipStream_t stream) {
    const float* x     = (const float*)d_in[0];
    const float* noise = (const float*)d_in[1];
    const float* wi    = (const float*)d_in[2];
    const float* si    = (const float*)d_in[3];
    const float* wrec  = (const float*)d_in[4];
    const float* wo    = (const float*)d_in[5];
    const float* so    = (const float*)d_in[6];
    const float* h0    = (const float*)d_in[7];
    float* out = (float*)d_out;
    unsigned long long* rtag = (unsigned long long*)d_ws;   // 512 KB

    (void)in_sizes; (void)n_in; (void)out_size; (void)ws_size;

    void* args[] = {(void*)&x, (void*)&noise, (void*)&wi, (void*)&si,
                    (void*)&wrec, (void*)&wo, (void*)&so, (void*)&h0,
                    (void*)&out, (void*)&rtag};
    hipLaunchCooperativeKernel((void*)rnn_kernel, dim3(NBLOCKS), dim3(NTHREADS),
                               args, 0, stream);
}